// Round 2
// baseline (28.153 us; speedup 1.0000x reference)
//
#include <hip/hip_runtime.h>

#define NBINS 256
#define ROWS 96                    // b*c = 32*3
#define ROW_N (512 * 512)          // 262144 elements per row
#define BLOCKS_PER_ROW 16
#define CHUNK (ROW_N / BLOCKS_PER_ROW)   // 16384 elements per block
#define BLOCK 256
#define WAVES (BLOCK / 64)
#define BIN_WIDTH 0.99609375f      // (255-0)/256, exactly representable

__global__ void nh_zero_out(float* __restrict__ out) {
    out[blockIdx.x * NBINS + threadIdx.x] = 0.0f;
}

__global__ __launch_bounds__(BLOCK) void nh_hist(const float* __restrict__ x,
                                                 float* __restrict__ out) {
    __shared__ unsigned int lh[WAVES][NBINS];
    const int tid = threadIdx.x;
    const int wave = tid >> 6;

    // zero LDS histograms
    #pragma unroll
    for (int i = tid; i < WAVES * NBINS; i += BLOCK)
        ((unsigned int*)lh)[i] = 0u;
    __syncthreads();

    const int row = blockIdx.y;
    const float4* __restrict__ p =
        (const float4*)(x + (size_t)row * ROW_N + (size_t)blockIdx.x * CHUNK);
    const int nvec = CHUNK / 4;   // 4096 float4 per block

    for (int i = tid; i < nvec; i += BLOCK) {
        float4 v = p[i];
        float f[4] = {v.x, v.y, v.z, v.w};
        #pragma unroll
        for (int k = 0; k < 4; ++k) {
            float fv = f[k];
            // match reference: idx = floor(x / bin_width); IEEE fp32 division
            // is correctly rounded, so this is bit-identical to jnp's binning.
            int b = (int)floorf(fv / BIN_WIDTH);
            if (fv == 255.0f) b = NBINS - 1;          // right-closed last bin
            if (fv >= 0.0f && fv <= 255.0f) {         // drop out-of-range
                b = b < 0 ? 0 : (b > NBINS - 1 ? NBINS - 1 : b);
                atomicAdd(&lh[wave][b], 1u);
            }
        }
    }
    __syncthreads();

    // per-bin reduce across waves, one float atomic per (block, bin).
    // Exact: partial = count * 2^-18, all intermediate sums are multiples of
    // 2^-18 with magnitude <= 1 (19 mantissa bits < 24) -> order-independent.
    unsigned int total = 0;
    #pragma unroll
    for (int w = 0; w < WAVES; ++w) total += lh[w][tid];
    const float scale = 1.0f / (float)ROW_N;
    atomicAdd(&out[row * NBINS + tid], (float)total * scale);
}

extern "C" void kernel_launch(void* const* d_in, const int* in_sizes, int n_in,
                              void* d_out, int out_size, void* d_ws, size_t ws_size,
                              hipStream_t stream) {
    const float* x = (const float*)d_in[0];
    float* out = (float*)d_out;

    nh_zero_out<<<ROWS, NBINS, 0, stream>>>(out);

    dim3 grid(BLOCKS_PER_ROW, ROWS);
    nh_hist<<<grid, BLOCK, 0, stream>>>(x, out);
}

// Round 3
// 23.269 us; speedup vs baseline: 1.2099x; 1.2099x over previous
//
#include <hip/hip_runtime.h>

#define NBINS 256
#define ROWS 96                    // b*c = 32*3
#define ROW_N (512 * 512)          // 262144 elements per row
#define BPR 16                     // blocks per row
#define CHUNK (ROW_N / BPR)        // 16384 elements per block
#define BLOCK 256
#define WAVES (BLOCK / 64)
#define BIN_W 0.99609375f          // (255-0)/256, exactly representable
#define RECIP_W 1.00392156862745098f  // fl(256/255)
#define WS_NEEDED ((size_t)ROWS * BPR * NBINS * sizeof(unsigned int))

// ---- shared inner loop: per-wave LDS histogram with trash slot ----
template <bool USE_WS>
__global__ __launch_bounds__(BLOCK) void nh_hist(const float* __restrict__ x,
                                                 unsigned int* __restrict__ ws,
                                                 float* __restrict__ out) {
    __shared__ unsigned int lh[WAVES][NBINS + 1];   // +1 = trash for invalid
    const int tid = threadIdx.x;
    const int wave = tid >> 6;

    #pragma unroll
    for (int i = tid; i < WAVES * (NBINS + 1); i += BLOCK)
        ((unsigned int*)lh)[i] = 0u;
    __syncthreads();

    const int row = blockIdx.y;
    const float4* __restrict__ p =
        (const float4*)(x + (size_t)row * ROW_N + (size_t)blockIdx.x * CHUNK);

    #pragma unroll 4
    for (int i = tid; i < CHUNK / 4; i += BLOCK) {
        float4 v = p[i];
        float f[4] = {v.x, v.y, v.z, v.w};
        #pragma unroll
        for (int k = 0; k < 4; ++k) {
            float fv = f[k];
            // b_est = floor-estimate of fv / BIN_W via multiply; |err| <= 1.
            int b = (int)(fv * RECIP_W);
            // exact fixup: b*BIN_W and (b+1)*BIN_W are EXACT in fp32 (b<=256,
            // b*255 < 2^17), so these compares compute true floor(fv/BIN_W).
            float t = (float)b * BIN_W;
            int d = (int)((t + BIN_W) <= fv) - (int)(t > fv);
            b += d;
            b = b > NBINS - 1 ? NBINS - 1 : b;   // also maps fv==255 -> 255
            // out-of-range values -> trash slot (branchless)
            bool valid = (fv >= 0.0f) && (fv <= 255.0f);
            int slot = valid ? b : NBINS;
            atomicAdd(&lh[wave][slot], 1u);
        }
    }
    __syncthreads();

    // cross-wave reduce for this block's 256 bins
    unsigned int total = 0;
    #pragma unroll
    for (int w = 0; w < WAVES; ++w) total += lh[w][tid];

    if (USE_WS) {
        // non-atomic partial: block owns ws[(row*BPR + bx)*NBINS + tid]
        ws[((size_t)row * BPR + blockIdx.x) * NBINS + tid] = total;
    } else {
        // fallback: float atomic into pre-zeroed out (exact: multiples of
        // 2^-18, magnitude <= 1 -> 19 mantissa bits < 24)
        atomicAdd(&out[row * NBINS + tid], (float)total * (1.0f / ROW_N));
    }
}

__global__ void nh_reduce(const unsigned int* __restrict__ ws,
                          float* __restrict__ out) {
    const int row = blockIdx.x;
    const int bin = threadIdx.x;
    unsigned int s = 0;
    #pragma unroll
    for (int j = 0; j < BPR; ++j)
        s += ws[((size_t)row * BPR + j) * NBINS + bin];
    out[row * NBINS + bin] = (float)s * (1.0f / ROW_N);  // exact convert+scale
}

__global__ void nh_zero_out(float* __restrict__ out) {
    out[blockIdx.x * NBINS + threadIdx.x] = 0.0f;
}

extern "C" void kernel_launch(void* const* d_in, const int* in_sizes, int n_in,
                              void* d_out, int out_size, void* d_ws, size_t ws_size,
                              hipStream_t stream) {
    const float* x = (const float*)d_in[0];
    float* out = (float*)d_out;
    unsigned int* ws = (unsigned int*)d_ws;

    dim3 grid(BPR, ROWS);
    if (ws_size >= WS_NEEDED) {
        nh_hist<true><<<grid, BLOCK, 0, stream>>>(x, ws, out);
        nh_reduce<<<ROWS, NBINS, 0, stream>>>(ws, out);
    } else {
        nh_zero_out<<<ROWS, NBINS, 0, stream>>>(out);
        nh_hist<false><<<grid, BLOCK, 0, stream>>>(x, ws, out);
    }
}